// Round 7
// baseline (7134.338 us; speedup 1.0000x reference)
//
#include <hip/hip_runtime.h>
#include <cstddef>
#include <cstdint>

// 2-layer LSTM decoder, B=2048, Z=64, H=256, D=8, T=250. fp32 in/out.
//
// R16 = R11 (3.08 ms, proven no-spill shell) + LDS-resident weight tiles.
// Model (survives R10-R15 nulls): during stream phases the per-CU L2->CU
// port (~56 B/cyc, from the 34.5 TB/s / 256 CU ubench) is saturated; step =
// stream(14k cyc) + VALU(8k) + MFMA(3k) mostly serial. Cutting stream BYTES
// is the only safe lever; LDS (128 B/cyc, separate pipe, 115 KB spare) holds
// each wave's first 12 tiles (L0 0..7 + L1 0..3 = 12 KB/wave, 96 KB/WG),
// loaded ONCE before the t-loop, consumed via ds_read_b128 at phase start
// (overlapping the in-flight global prefetches). Stream 768->672 KB/step.
//  - breg[8] -> breg[4] (R10: depth-neutral; frees 16 VGPRs for ds temps).
//  - all streamed segment lengths & wrap offsets are 0 mod 4 -> slot=j&3
//    consistent across phases/steps (L0 streams 8..31, wraps to L1 tile 4;
//    L1 streams 4..63, wraps to next-step L0 tile 8).
// LDS 148.6 KB (1 WG/CU). Pack/layout/barriers byte-identical to R11.
// Watch: VGPR<=128, FETCH ~14 MB / WRITE ~25 MB (explosion = spill, revert).

#define BSZ    2048
#define ZDIM   64
#define HDIM   256
#define DDIM   8
#define TSTEPS 250
#define ROWS   16
#define NWG    (BSZ / ROWS)   // 128
#define NTH    512            // 8 waves
#define G4     1024
#define WSTR   264            // h1f/woutT row stride (shorts)

typedef __attribute__((ext_vector_type(4))) int v4i;

__device__ __forceinline__ unsigned short f2bf(float x) {   // RNE f32->bf16
  union { float f; unsigned u; } v; v.f = x;
  unsigned r = v.u + 0x7fff + ((v.u >> 16) & 1);
  return (unsigned short)(r >> 16);
}
__device__ __forceinline__ float bf2f(unsigned short b) {
  union { unsigned u; float f; } v; v.u = (unsigned)b << 16; return v.f;
}
__device__ __forceinline__ float fexp2(float x) { return __builtin_amdgcn_exp2f(x); }
__device__ __forceinline__ float frcp(float x)  { return __builtin_amdgcn_rcpf(x); }
__device__ __forceinline__ float sigm(float x)  { return frcp(1.f + fexp2(-1.44269504f * x)); }
__device__ __forceinline__ float tanh_(float x) { return 2.f * frcp(1.f + fexp2(-2.88539008f * x)) - 1.f; }
__device__ __forceinline__ char q8(float x, float s) {
  float v = fminf(fmaxf(x * s, -127.f), 127.f);
  return (char)(int)__builtin_rintf(v);
}
// h*s split into hi + lo/254 (lo in [-127,127] exactly since 0.5*254=127)
__device__ __forceinline__ void q8pair(float h, float s, char* hi, char* lo) {
  float hs = fminf(fmaxf(h * s, -127.f), 127.f);
  float hq = __builtin_rintf(hs);
  *hi = (char)(int)hq;
  *lo = (char)(int)__builtin_rintf((hs - hq) * 254.f);
}

// ---------------- initial state (mapping verified R1-R8) ----------------
__global__ void init_state(const float* __restrict__ z,
                           const float* __restrict__ Wfh, const float* __restrict__ bfh,
                           const float* __restrict__ Wfc, const float* __restrict__ bfc,
                           char* __restrict__ h0h, char* __restrict__ h0l,
                           char* __restrict__ h1h, char* __restrict__ h1l,
                           float* __restrict__ c0s, float* __restrict__ c1s)
{
  int idx = blockIdx.x * 256 + threadIdx.x;
  int b = idx >> 8;
  int j = idx & 255;
  int col = ((b & 1) << 8) | j;
  const float* z0 = z + (size_t)(b >> 1) * ZDIM;
  const float* z1 = z + (size_t)(1024 + (b >> 1)) * ZDIM;
  float h0 = bfh[col], c0v = bfc[col], h1 = bfh[col], c1v = bfc[col];
  for (int k = 0; k < ZDIM; ++k) {
    float wh = Wfh[k * 512 + col];
    float wc = Wfc[k * 512 + col];
    float a = z0[k], bb = z1[k];
    h0  += a * wh;  c0v += a * wc;
    h1  += bb * wh; c1v += bb * wc;
  }
  char hi, lo;
  q8pair(h0, 31.75f, &hi, &lo); h0h[idx] = hi; h0l[idx] = lo;
  q8pair(h1, 31.75f, &hi, &lo); h1h[idx] = hi; h1l[idx] = lo;
  c0s[idx] = c0v; c1s[idx] = c1v;
}

// ---------------- per-output-column scales (unchanged) ----------------
__global__ void col_scales(const float* __restrict__ Whh0,
                           const float* __restrict__ Wih1, const float* __restrict__ Whh1,
                           float* __restrict__ cs0, float* __restrict__ qs0,
                           float* __restrict__ cs1, float* __restrict__ qs1)
{
  int c = blockIdx.x * 256 + threadIdx.x;   // 0..2047
  if (c < 1024) {
    float m = 0.f;
    for (int k = 0; k < 256; ++k) m = fmaxf(m, fabsf(Whh0[(size_t)k * G4 + c]));
    cs0[c] = m * (1.f / 16129.f);
    qs0[c] = 127.f / m;
  } else {
    c -= 1024;
    float m = 0.f;
    for (int k = 0; k < 256; ++k) m = fmaxf(m, fabsf(Whh1[(size_t)k * G4 + c]));
    for (int k = 0; k < 256; ++k) m = fmaxf(m, fabsf(Wih1[(size_t)k * G4 + c]));
    cs1[c] = m * (1.f / 16129.f);
    qs1[c] = 127.f / m;
  }
}

// ---- i8 weight pack: per-wave-contiguous linear stream (verified R8) ----
__global__ void pack_i8(const float* __restrict__ Whh0,
                        const float* __restrict__ Wih1, const float* __restrict__ Whh1,
                        const float* __restrict__ qs0, const float* __restrict__ qs1,
                        char* __restrict__ p0, char* __restrict__ p1)
{
  int tt   = blockIdx.x * 4 + (threadIdx.x >> 6);   // 0..767
  int lane = threadIdx.x & 63;
  int l15 = lane & 15, lq = lane >> 4;
  union { char c[16]; uint4 u; } v;
  if (tt < 256) {                                   // layer0: w*4+kc, i
    int w = tt >> 5, kc = (tt >> 3) & 3, i = tt & 7;
    int nt = (i >> 1) * 16 + 2 * w + (i & 1);
    int col = nt * 16 + l15;
    float q = qs0[col];
    for (int j = 0; j < 16; ++j) {
      int k = kc * 64 + lq * 16 + j;
      v.c[j] = q8(Whh0[(size_t)k * G4 + col], q);
    }
    *(uint4*)(p0 + (size_t)tt * 1024 + lane * 16) = v.u;
  } else {                                          // layer1: w*8+kc, i
    int t1 = tt - 256;
    int w = t1 >> 6, kc = (t1 >> 3) & 7, i = t1 & 7;
    int nt = (i >> 1) * 16 + 2 * w + (i & 1);
    int col = nt * 16 + l15;
    float q = qs1[col];
    for (int j = 0; j < 16; ++j) {
      int k = kc * 64 + lq * 16 + j;
      float wv = (k < 256) ? Whh1[(size_t)k * G4 + col]
                           : Wih1[(size_t)(k - 256) * G4 + col];
      v.c[j] = q8(wv, q);
    }
    *(uint4*)(p1 + (size_t)t1 * 1024 + lane * 16) = v.u;
  }
}

// ---------------- persistent LSTM kernel ----------------
__global__ __launch_bounds__(NTH, 1) void lstm_run(
    const float* __restrict__ target,
    const char* __restrict__ p0, const char* __restrict__ p1,
    const float* __restrict__ bih0, const float* __restrict__ bhh0,
    const float* __restrict__ bih1, const float* __restrict__ bhh1,
    const float* __restrict__ Wih0,            // [8,1024] fp32 -> 64 VGPRs/thread
    const float* __restrict__ Wout, const float* __restrict__ bout,
    const char* __restrict__ h0h, const char* __restrict__ h0l,
    const char* __restrict__ h1h, const char* __restrict__ h1l,
    const float* __restrict__ c0s, const float* __restrict__ c1s,
    const float* __restrict__ cs0, const float* __restrict__ cs1,
    float* __restrict__ out)
{
  // double-buffered activation planes: [buf][32 blk-rows * 16], buf = 512 uint4
  __shared__ uint4 X4h[1024];                      // 16 KB
  __shared__ uint4 X4l[1024];                      // 16 KB
  __shared__ unsigned short h1f[2][16 * WSTR];     // 16.5 KB bf16 h1 (out-proj)
  __shared__ unsigned short woutT[8 * WSTR];       // 4.1 KB bf16
  __shared__ uint4 wres[8 * 12 * 64];              // 96 KB resident weight tiles
                                                   // total ~148.6 KB
  const int tid  = threadIdx.x;
  const int w    = tid >> 6;
  const int lane = tid & 63;
  const int l15  = lane & 15;
  const int lq   = lane >> 4;
  const int b0   = blockIdx.x * ROWS;
  char* Xch = (char*)X4h;
  char* Xcl = (char*)X4l;

  // ---- one-time staging into buffer 0 ----
  {
    int m = tid & 15, blk = tid >> 4;              // 32 blks x 16 m
    const char* sh = (blk < 16) ? h1h : h0h;
    const char* sl = (blk < 16) ? h1l : h0l;
    int jblk = blk & 15;
    X4h[blk * 16 + m] = *(const uint4*)(sh + (size_t)(b0 + m) * HDIM + jblk * 16);
    X4l[blk * 16 + m] = *(const uint4*)(sl + (size_t)(b0 + m) * HDIM + jblk * 16);
  }
  for (int i = tid; i < HDIM * DDIM; i += NTH) {
    int k = i >> 3, d = i & 7;
    woutT[d * WSTR + k] = f2bf(Wout[i]);
  }

  const int myrow = lq * 4;
  const int jc0   = 32 * w + l15;
  float c0r[2][4], c1r[2][4];
  float bA0[8], bA1[8], csA0[8], csA1[8];          // flat [g*2+cc]
  float wx[8][8];                                  // Wih0[d][col(i)] in regs
#pragma unroll
  for (int i = 0; i < 8; ++i) {
    int col = (i >> 1) * 256 + jc0 + 16 * (i & 1);
    bA0[i]  = bih0[col] + bhh0[col];
    bA1[i]  = bih1[col] + bhh1[col];
    csA0[i] = cs0[col];
    csA1[i] = cs1[col];
#pragma unroll
    for (int d = 0; d < 8; ++d) wx[i][d] = Wih0[d * G4 + col];
  }
#pragma unroll
  for (int cc = 0; cc < 2; ++cc) {
    int j = jc0 + cc * 16;
#pragma unroll
    for (int r = 0; r < 4; ++r) {
      c0r[cc][r] = c0s[(size_t)(b0 + myrow + r) * HDIM + j];
      c1r[cc][r] = c1s[(size_t)(b0 + myrow + r) * HDIM + j];
    }
  }
  const int opr = tid >> 5, opd = (tid >> 2) & 7, opq = tid & 3;
  const float bo_out = bout[opd];

  // per-lane weight stream bases; tile j at base + j*1024 (linear)
  const char* gp0 = p0 + (size_t)w * 32768 + lane * 16;
  const char* gp1 = p1 + (size_t)w * 65536 + lane * 16;

  // ---- resident weight tiles: L0 tiles 0..7, L1 tiles 0..3 (per wave) ----
#pragma unroll
  for (int j = 0; j < 8; ++j)
    wres[w * 768 + j * 64 + lane] = *(const uint4*)(gp0 + (size_t)j * 1024);
#pragma unroll
  for (int j = 0; j < 4; ++j)
    wres[w * 768 + 512 + j * 64 + lane] = *(const uint4*)(gp1 + (size_t)j * 1024);

  // 4-deep direct global->VGPR stream for the non-resident tiles.
  // prologue: L0 streamed tiles 8..11 -> breg[0..3]  (8%4==0 -> slot=j&3)
  v4i breg[4];
#pragma unroll
  for (int s = 0; s < 4; ++s)
    breg[s] = *(const v4i*)(gp0 + (size_t)(8 + s) * 1024);

  __syncthreads();

#pragma unroll 1
  for (int t = 0; t < TSTEPS; ++t) {
    const int xc = (t & 1) << 9;                   // uint4-index base of X_cur
    const int xn = xc ^ 512;                       // X_next

    // ---- teacher-forced input: each thread loads its own 4 rows ----
    float4 xa[4], xb[4];
    if (t > 0) {
      const float* xp = target + (size_t)(b0 + myrow) * (TSTEPS * DDIM)
                               + (size_t)(t - 1) * DDIM;
#pragma unroll
      for (int r = 0; r < 4; ++r) {
        xa[r] = *(const float4*)(xp + (size_t)r * (TSTEPS * DDIM));
        xb[r] = *(const float4*)(xp + (size_t)r * (TSTEPS * DDIM) + 4);
      }
    } else {
#pragma unroll
      for (int r = 0; r < 4; ++r) {
        xa[r] = make_float4(0.f, 0.f, 0.f, 0.f);
        xb[r] = make_float4(0.f, 0.f, 0.f, 0.f);
      }
    }

    const float sc0 = (t <= 1) ? 4.f : 1.f;
    const float sc1 = (t == 0) ? 4.f : 1.f;
    const float wq0 = (t == 0) ? 31.75f : 127.f;

    v4i acch[8], accl[8];
    const v4i zi = {0, 0, 0, 0};

    // ============ layer 0: h0 @ Whh0 ============
#pragma unroll
    for (int i = 0; i < 8; ++i) { acch[i] = zi; accl[i] = zi; }
    {
      v4i ah, al;
      {                                            // kc=0 A-fragment
        int aidx = xc + (16 + lq) * 16 + l15;
        ah = __builtin_bit_cast(v4i, X4h[aidx]);
        al = __builtin_bit_cast(v4i, X4l[aidx]);
      }
      // resident tiles 0..7 (kc=0, i=j) from LDS
#pragma unroll
      for (int j = 0; j < 8; ++j) {
        v4i bb = __builtin_bit_cast(v4i, wres[w * 768 + j * 64 + lane]);
        acch[j] = __builtin_amdgcn_mfma_i32_16x16x64_i8(ah, bb, acch[j], 0, 0, 0);
        accl[j] = __builtin_amdgcn_mfma_i32_16x16x64_i8(al, bb, accl[j], 0, 0, 0);
      }
      // streamed tiles 8..31
#pragma unroll
      for (int j = 8; j < 32; ++j) {
        const int i = j & 7, s = j & 3;
        if (i == 0) {
          int kc = j >> 3;
          int aidx = xc + (16 + kc * 4 + lq) * 16 + l15;
          ah = __builtin_bit_cast(v4i, X4h[aidx]);
          al = __builtin_bit_cast(v4i, X4l[aidx]);
        }
        v4i bb = breg[s];
        acch[i] = __builtin_amdgcn_mfma_i32_16x16x64_i8(ah, bb, acch[i], 0, 0, 0);
        accl[i] = __builtin_amdgcn_mfma_i32_16x16x64_i8(al, bb, accl[i], 0, 0, 0);
        const int jn = j + 4;
        breg[s] = (jn < 32) ? *(const v4i*)(gp0 + (size_t)jn * 1024)
                            : *(const v4i*)(gp1 + (size_t)(jn - 32 + 4) * 1024);
      }
    }

    // ---- deferred out-projection for step t-1 (overlaps stream stalls) ----
    if (t > 0) {
      const unsigned short* hf = h1f[(t & 1) ^ 1];
      float s_ = 0.f;
#pragma unroll
      for (int i = 0; i < 16; ++i) {
        ushort4 hx = *(const ushort4*)&hf[opr * WSTR + i * 16 + opq * 4];
        ushort4 wv = *(const ushort4*)&woutT[opd * WSTR + i * 16 + opq * 4];
        s_ += bf2f(hx.x) * bf2f(wv.x) + bf2f(hx.y) * bf2f(wv.y)
            + bf2f(hx.z) * bf2f(wv.z) + bf2f(hx.w) * bf2f(wv.w);
      }
      s_ += __shfl_xor(s_, 1);
      s_ += __shfl_xor(s_, 2);
      if (opq == 0)
        out[(size_t)(b0 + opr) * (TSTEPS * DDIM) + (size_t)(t - 1) * DDIM + opd] =
            s_ + bo_out;
    }

    // ---- cell 0: dequant + fp32 x-path; writes h0(t) into X_next ----
    {
#pragma unroll
      for (int cc = 0; cc < 2; ++cc) {
        float gf4[4][4];
#pragma unroll
        for (int g = 0; g < 4; ++g) {
          int i = g * 2 + cc;
          float cs = csA0[i] * sc0;
#pragma unroll
          for (int r = 0; r < 4; ++r)
            gf4[g][r] = ((float)acch[i][r] + (float)accl[i][r] * (1.f / 254.f)) * cs + bA0[i];
        }
#pragma unroll
        for (int g = 0; g < 4; ++g) {
          int i = g * 2 + cc;
#pragma unroll
          for (int r = 0; r < 4; ++r)
            gf4[g][r] += xa[r].x * wx[i][0] + xa[r].y * wx[i][1]
                       + xa[r].z * wx[i][2] + xa[r].w * wx[i][3]
                       + xb[r].x * wx[i][4] + xb[r].y * wx[i][5]
                       + xb[r].z * wx[i][6] + xb[r].w * wx[i][7];
        }
#pragma unroll
        for (int r = 0; r < 4; ++r) {
          float iv = sigm(gf4[0][r]);
          float fv = sigm(gf4[1][r]);
          float gv = tanh_(gf4[2][r]);
          float ov = sigm(gf4[3][r]);
          c0r[cc][r] = fv * c0r[cc][r] + iv * gv;
          char hi, lo;
          q8pair(ov * tanh_(c0r[cc][r]), wq0, &hi, &lo);
          int off = (xn + (16 + 2 * w + cc) * 16 + myrow + r) * 16 + l15;
          Xch[off] = hi; Xcl[off] = lo;
        }
      }
    }
    __syncthreads();   // (B) h0(t) visible; L1 streamed tiles 4..7 in flight/landed

    // ====== layer 1: [h1(t-1) | h0(t)] @ W1 ======
#pragma unroll
    for (int i = 0; i < 8; ++i) { acch[i] = zi; accl[i] = zi; }
    {
      v4i ah, al;
      {                                            // kc=0 -> h1 (cur buffer)
        int aidx = xc + lq * 16 + l15;
        ah = __builtin_bit_cast(v4i, X4h[aidx]);
        al = __builtin_bit_cast(v4i, X4l[aidx]);
      }
      // resident tiles 0..3 (kc=0, i=j) from LDS
#pragma unroll
      for (int j = 0; j < 4; ++j) {
        v4i bb = __builtin_bit_cast(v4i, wres[w * 768 + 512 + j * 64 + lane]);
        acch[j] = __builtin_amdgcn_mfma_i32_16x16x64_i8(ah, bb, acch[j], 0, 0, 0);
        accl[j] = __builtin_amdgcn_mfma_i32_16x16x64_i8(al, bb, accl[j], 0, 0, 0);
      }
      // streamed tiles 4..63
#pragma unroll
      for (int j = 4; j < 64; ++j) {
        const int i = j & 7, s = j & 3;
        if (i == 0) {
          int kc = j >> 3;                         // 0..3 h1 (cur), 4..7 h0' (next)
          int aidx = (kc < 4) ? (xc + (kc * 4 + lq) * 16 + l15)
                              : (xn + (16 + (kc - 4) * 4 + lq) * 16 + l15);
          ah = __builtin_bit_cast(v4i, X4h[aidx]);
          al = __builtin_bit_cast(v4i, X4l[aidx]);
        }
        v4i bb = breg[s];
        acch[i] = __builtin_amdgcn_mfma_i32_16x16x64_i8(ah, bb, acch[i], 0, 0, 0);
        accl[i] = __builtin_amdgcn_mfma_i32_16x16x64_i8(al, bb, accl[i], 0, 0, 0);
        const int jn = j + 4;
        breg[s] = (jn < 64) ? *(const v4i*)(gp1 + (size_t)jn * 1024)
                            : *(const v4i*)(gp0 + (size_t)(jn - 64 + 8) * 1024);
      }
    }

    // ---- cell 1: writes h1(t) into X_next + bf16 h1f[t&1] ----
#pragma unroll
    for (int cc = 0; cc < 2; ++cc)
#pragma unroll
      for (int r = 0; r < 4; ++r) {
        float di = ((float)acch[0 + cc][r] + (float)accl[0 + cc][r] * (1.f / 254.f));
        float df = ((float)acch[2 + cc][r] + (float)accl[2 + cc][r] * (1.f / 254.f));
        float dg = ((float)acch[4 + cc][r] + (float)accl[4 + cc][r] * (1.f / 254.f));
        float dv = ((float)acch[6 + cc][r] + (float)accl[6 + cc][r] * (1.f / 254.f));
        float iv = sigm(di * csA1[0 + cc] * sc1 + bA1[0 + cc]);
        float fv = sigm(df * csA1[2 + cc] * sc1 + bA1[2 + cc]);
        float gv = tanh_(dg * csA1[4 + cc] * sc1 + bA1[4 + cc]);
        float ov = sigm(dv * csA1[6 + cc] * sc1 + bA1[6 + cc]);
        c1r[cc][r] = fv * c1r[cc][r] + iv * gv;
        float h = ov * tanh_(c1r[cc][r]);
        char hi, lo;
        q8pair(h, 127.f, &hi, &lo);
        int off = (xn + (2 * w + cc) * 16 + myrow + r) * 16 + l15;
        Xch[off] = hi; Xcl[off] = lo;
        h1f[t & 1][(myrow + r) * WSTR + jc0 + cc * 16] = f2bf(h);
      }
    __syncthreads();   // (F) h1(t)/h1f visible; next-step L0 tiles 8..11 in flight
  }

  // ---- epilogue: out-projection for the final step ----
  {
    const unsigned short* hf = h1f[(TSTEPS - 1) & 1];
    float s_ = 0.f;
#pragma unroll
    for (int i = 0; i < 16; ++i) {
      ushort4 hx = *(const ushort4*)&hf[opr * WSTR + i * 16 + opq * 4];
      ushort4 wv = *(const ushort4*)&woutT[opd * WSTR + i * 16 + opq * 4];
      s_ += bf2f(hx.x) * bf2f(wv.x) + bf2f(hx.y) * bf2f(wv.y)
          + bf2f(hx.z) * bf2f(wv.z) + bf2f(hx.w) * bf2f(wv.w);
    }
    s_ += __shfl_xor(s_, 1);
    s_ += __shfl_xor(s_, 2);
    if (opq == 0)
      out[(size_t)(b0 + opr) * (TSTEPS * DDIM) + (size_t)(TSTEPS - 1) * DDIM + opd] =
          s_ + bo_out;
  }
}

extern "C" void kernel_launch(void* const* d_in, const int* in_sizes, int n_in,
                              void* d_out, int out_size, void* d_ws, size_t ws_size,
                              hipStream_t stream) {
  const float* z    = (const float*)d_in[0];
  const float* tgt  = (const float*)d_in[1];
  const float* Wfh  = (const float*)d_in[2];
  const float* bfh  = (const float*)d_in[3];
  const float* Wfc  = (const float*)d_in[4];
  const float* bfc  = (const float*)d_in[5];
  const float* Wih0 = (const float*)d_in[6];
  const float* Whh0 = (const float*)d_in[7];
  const float* bih0 = (const float*)d_in[8];
  const float* bhh0 = (const float*)d_in[9];
  const float* Wih1 = (const float*)d_in[10];
  const float* Whh1 = (const float*)d_in[11];
  const float* bih1 = (const float*)d_in[12];
  const float* bhh1 = (const float*)d_in[13];
  const float* Wout = (const float*)d_in[14];
  const float* bout = (const float*)d_in[15];

  // ws layout (bytes), total ~7.09 MB
  char* ws = (char*)d_ws;
  char*  p0   = ws;                                  // 262,144
  char*  p1   = ws + 262144;                         // 524,288
  char*  h0h  = ws + 786432;                         // 524,288
  char*  h0l  = ws + 1310720;                        // 524,288
  char*  h1h  = ws + 1835008;                        // 524,288
  char*  h1l  = ws + 2359296;                        // 524,288
  float* c0s  = (float*)(ws + 2883584);              // 2,097,152
  float* c1s  = (float*)(ws + 4980736);              // 2,097,152
  float* cs0  = (float*)(ws + 7077888);              // 4,096
  float* qs0  = (float*)(ws + 7081984);              // 4,096
  float* cs1  = (float*)(ws + 7086080);              // 4,096
  float* qs1  = (float*)(ws + 7090176);              // 4,096

  hipLaunchKernelGGL(init_state, dim3(BSZ * HDIM / 256), dim3(256), 0, stream,
                     z, Wfh, bfh, Wfc, bfc, h0h, h0l, h1h, h1l, c0s, c1s);
  hipLaunchKernelGGL(col_scales, dim3(8), dim3(256), 0, stream,
                     Whh0, Wih1, Whh1, cs0, qs0, cs1, qs1);
  hipLaunchKernelGGL(pack_i8, dim3(192), dim3(256), 0, stream,
                     Whh0, Wih1, Whh1, qs0, qs1, p0, p1);
  hipLaunchKernelGGL(lstm_run, dim3(NWG), dim3(NTH), 0, stream,
                     tgt, p0, p1, bih0, bhh0, bih1, bhh1, Wih0, Wout, bout,
                     h0h, h0l, h1h, h1l, c0s, c1s, cs0, cs1, (float*)d_out);
}

// Round 8
// 2762.135 us; speedup vs baseline: 2.5829x; 2.5829x over previous
//
#include <hip/hip_runtime.h>
#include <cstddef>
#include <cstdint>

// 2-layer LSTM decoder, B=2048, Z=64, H=256, D=8, T=250. fp32 in/out.
//
// R17 = R11 (3.08 ms, proven shell) + 8 LDS-resident L0 tiles, with the
// register budget PAID FOR first. R16's lesson: R11 sits at exactly 128
// VGPRs; adding the resident ds_read path while keeping wx[8][8] (64 regs)
// spilled (FETCH 11 GB scratch thrash). This round:
//  - wx[8][8] -> LDS fp32 tables wxa4/wxb4 (32 KB, R13-verified mapping):
//    frees 64 persistent VGPRs. Net register delta vs R11 ~ -50.
//  - wres: per-wave L0 tiles 0..7 (64 KB total), loaded ONCE pre-loop,
//    consumed via explicit 2-slot rotation rb[(j+1)&1] (fully unrolled,
//    static indices, max 8 live regs -> hoist-proof). Stream 768->704
//    KB/step (-8.3% of the port-bound phase).
//  - streamed L0 8..31 (slot=j&7, prologue tiles 8..15); L1 0..63 as R11;
//    L1 tail wraps to next-step L0 tiles 8..15 (skip resident 0..7).
// LDS 148.6 KB (1 WG/CU). Pack/cell/outproj/barriers byte-identical R11.
// Go/no-go: VGPR<=128, FETCH ~15 MB, WRITE ~25 MB (explosion = spill).

#define BSZ    2048
#define ZDIM   64
#define HDIM   256
#define DDIM   8
#define TSTEPS 250
#define ROWS   16
#define NWG    (BSZ / ROWS)   // 128
#define NTH    512            // 8 waves
#define G4     1024
#define WSTR   264            // h1f/woutT row stride (shorts)

typedef __attribute__((ext_vector_type(4))) int v4i;

__device__ __forceinline__ unsigned short f2bf(float x) {   // RNE f32->bf16
  union { float f; unsigned u; } v; v.f = x;
  unsigned r = v.u + 0x7fff + ((v.u >> 16) & 1);
  return (unsigned short)(r >> 16);
}
__device__ __forceinline__ float bf2f(unsigned short b) {
  union { unsigned u; float f; } v; v.u = (unsigned)b << 16; return v.f;
}
__device__ __forceinline__ float fexp2(float x) { return __builtin_amdgcn_exp2f(x); }
__device__ __forceinline__ float frcp(float x)  { return __builtin_amdgcn_rcpf(x); }
__device__ __forceinline__ float sigm(float x)  { return frcp(1.f + fexp2(-1.44269504f * x)); }
__device__ __forceinline__ float tanh_(float x) { return 2.f * frcp(1.f + fexp2(-2.88539008f * x)) - 1.f; }
__device__ __forceinline__ char q8(float x, float s) {
  float v = fminf(fmaxf(x * s, -127.f), 127.f);
  return (char)(int)__builtin_rintf(v);
}
// h*s split into hi + lo/254 (lo in [-127,127] exactly since 0.5*254=127)
__device__ __forceinline__ void q8pair(float h, float s, char* hi, char* lo) {
  float hs = fminf(fmaxf(h * s, -127.f), 127.f);
  float hq = __builtin_rintf(hs);
  *hi = (char)(int)hq;
  *lo = (char)(int)__builtin_rintf((hs - hq) * 254.f);
}

// ---------------- initial state (mapping verified R1-R8) ----------------
__global__ void init_state(const float* __restrict__ z,
                           const float* __restrict__ Wfh, const float* __restrict__ bfh,
                           const float* __restrict__ Wfc, const float* __restrict__ bfc,
                           char* __restrict__ h0h, char* __restrict__ h0l,
                           char* __restrict__ h1h, char* __restrict__ h1l,
                           float* __restrict__ c0s, float* __restrict__ c1s)
{
  int idx = blockIdx.x * 256 + threadIdx.x;
  int b = idx >> 8;
  int j = idx & 255;
  int col = ((b & 1) << 8) | j;
  const float* z0 = z + (size_t)(b >> 1) * ZDIM;
  const float* z1 = z + (size_t)(1024 + (b >> 1)) * ZDIM;
  float h0 = bfh[col], c0v = bfc[col], h1 = bfh[col], c1v = bfc[col];
  for (int k = 0; k < ZDIM; ++k) {
    float wh = Wfh[k * 512 + col];
    float wc = Wfc[k * 512 + col];
    float a = z0[k], bb = z1[k];
    h0  += a * wh;  c0v += a * wc;
    h1  += bb * wh; c1v += bb * wc;
  }
  char hi, lo;
  q8pair(h0, 31.75f, &hi, &lo); h0h[idx] = hi; h0l[idx] = lo;
  q8pair(h1, 31.75f, &hi, &lo); h1h[idx] = hi; h1l[idx] = lo;
  c0s[idx] = c0v; c1s[idx] = c1v;
}

// ---------------- per-output-column scales (unchanged) ----------------
__global__ void col_scales(const float* __restrict__ Whh0,
                           const float* __restrict__ Wih1, const float* __restrict__ Whh1,
                           float* __restrict__ cs0, float* __restrict__ qs0,
                           float* __restrict__ cs1, float* __restrict__ qs1)
{
  int c = blockIdx.x * 256 + threadIdx.x;   // 0..2047
  if (c < 1024) {
    float m = 0.f;
    for (int k = 0; k < 256; ++k) m = fmaxf(m, fabsf(Whh0[(size_t)k * G4 + c]));
    cs0[c] = m * (1.f / 16129.f);
    qs0[c] = 127.f / m;
  } else {
    c -= 1024;
    float m = 0.f;
    for (int k = 0; k < 256; ++k) m = fmaxf(m, fabsf(Whh1[(size_t)k * G4 + c]));
    for (int k = 0; k < 256; ++k) m = fmaxf(m, fabsf(Wih1[(size_t)k * G4 + c]));
    cs1[c] = m * (1.f / 16129.f);
    qs1[c] = 127.f / m;
  }
}

// ---- i8 weight pack: per-wave-contiguous linear stream (verified R8) ----
__global__ void pack_i8(const float* __restrict__ Whh0,
                        const float* __restrict__ Wih1, const float* __restrict__ Whh1,
                        const float* __restrict__ qs0, const float* __restrict__ qs1,
                        char* __restrict__ p0, char* __restrict__ p1)
{
  int tt   = blockIdx.x * 4 + (threadIdx.x >> 6);   // 0..767
  int lane = threadIdx.x & 63;
  int l15 = lane & 15, lq = lane >> 4;
  union { char c[16]; uint4 u; } v;
  if (tt < 256) {                                   // layer0: w*4+kc, i
    int w = tt >> 5, kc = (tt >> 3) & 3, i = tt & 7;
    int nt = (i >> 1) * 16 + 2 * w + (i & 1);
    int col = nt * 16 + l15;
    float q = qs0[col];
    for (int j = 0; j < 16; ++j) {
      int k = kc * 64 + lq * 16 + j;
      v.c[j] = q8(Whh0[(size_t)k * G4 + col], q);
    }
    *(uint4*)(p0 + (size_t)tt * 1024 + lane * 16) = v.u;
  } else {                                          // layer1: w*8+kc, i
    int t1 = tt - 256;
    int w = t1 >> 6, kc = (t1 >> 3) & 7, i = t1 & 7;
    int nt = (i >> 1) * 16 + 2 * w + (i & 1);
    int col = nt * 16 + l15;
    float q = qs1[col];
    for (int j = 0; j < 16; ++j) {
      int k = kc * 64 + lq * 16 + j;
      float wv = (k < 256) ? Whh1[(size_t)k * G4 + col]
                           : Wih1[(size_t)(k - 256) * G4 + col];
      v.c[j] = q8(wv, q);
    }
    *(uint4*)(p1 + (size_t)t1 * 1024 + lane * 16) = v.u;
  }
}

// ---------------- persistent LSTM kernel ----------------
__global__ __launch_bounds__(NTH, 1) void lstm_run(
    const float* __restrict__ target,
    const char* __restrict__ p0, const char* __restrict__ p1,
    const float* __restrict__ bih0, const float* __restrict__ bhh0,
    const float* __restrict__ bih1, const float* __restrict__ bhh1,
    const float* __restrict__ Wih0,            // [8,1024] fp32 -> LDS tables
    const float* __restrict__ Wout, const float* __restrict__ bout,
    const char* __restrict__ h0h, const char* __restrict__ h0l,
    const char* __restrict__ h1h, const char* __restrict__ h1l,
    const float* __restrict__ c0s, const float* __restrict__ c1s,
    const float* __restrict__ cs0, const float* __restrict__ cs1,
    float* __restrict__ out)
{
  // double-buffered activation planes: [buf][32 blk-rows * 16], buf = 512 uint4
  __shared__ uint4 X4h[1024];                      // 16 KB
  __shared__ uint4 X4l[1024];                      // 16 KB
  __shared__ unsigned short h1f[2][16 * WSTR];     // 16.5 KB bf16 h1 (out-proj)
  __shared__ unsigned short woutT[8 * WSTR];       // 4.1 KB bf16
  __shared__ float4 wxa4[1024];                    // 16 KB Wih0 d=0..3 per col
  __shared__ float4 wxb4[1024];                    // 16 KB Wih0 d=4..7 per col
  __shared__ uint4 wres[8 * 8 * 64];               // 64 KB resident L0 tiles 0..7
                                                   // total ~148.6 KB
  const int tid  = threadIdx.x;
  const int w    = tid >> 6;
  const int lane = tid & 63;
  const int l15  = lane & 15;
  const int lq   = lane >> 4;
  const int b0   = blockIdx.x * ROWS;
  char* Xch = (char*)X4h;
  char* Xcl = (char*)X4l;

  // ---- one-time staging into buffer 0 ----
  {
    int m = tid & 15, blk = tid >> 4;              // 32 blks x 16 m
    const char* sh = (blk < 16) ? h1h : h0h;
    const char* sl = (blk < 16) ? h1l : h0l;
    int jblk = blk & 15;
    X4h[blk * 16 + m] = *(const uint4*)(sh + (size_t)(b0 + m) * HDIM + jblk * 16);
    X4l[blk * 16 + m] = *(const uint4*)(sl + (size_t)(b0 + m) * HDIM + jblk * 16);
  }
  for (int i = tid; i < HDIM * DDIM; i += NTH) {
    int k = i >> 3, d = i & 7;
    woutT[d * WSTR + k] = f2bf(Wout[i]);
  }
  for (int i = tid; i < G4; i += NTH) {
    wxa4[i] = make_float4(Wih0[0 * G4 + i], Wih0[1 * G4 + i],
                          Wih0[2 * G4 + i], Wih0[3 * G4 + i]);
    wxb4[i] = make_float4(Wih0[4 * G4 + i], Wih0[5 * G4 + i],
                          Wih0[6 * G4 + i], Wih0[7 * G4 + i]);
  }

  const int myrow = lq * 4;
  const int jc0   = 32 * w + l15;
  float c0r[2][4], c1r[2][4];
  float bA0[8], bA1[8], csA0[8], csA1[8];          // flat [g*2+cc]
#pragma unroll
  for (int i = 0; i < 8; ++i) {
    int col = (i >> 1) * 256 + jc0 + 16 * (i & 1);
    bA0[i]  = bih0[col] + bhh0[col];
    bA1[i]  = bih1[col] + bhh1[col];
    csA0[i] = cs0[col];
    csA1[i] = cs1[col];
  }
#pragma unroll
  for (int cc = 0; cc < 2; ++cc) {
    int j = jc0 + cc * 16;
#pragma unroll
    for (int r = 0; r < 4; ++r) {
      c0r[cc][r] = c0s[(size_t)(b0 + myrow + r) * HDIM + j];
      c1r[cc][r] = c1s[(size_t)(b0 + myrow + r) * HDIM + j];
    }
  }
  const int opr = tid >> 5, opd = (tid >> 2) & 7, opq = tid & 3;
  const float bo_out = bout[opd];

  // per-lane weight stream bases; tile j at base + j*1024 (linear)
  const char* gp0 = p0 + (size_t)w * 32768 + lane * 16;
  const char* gp1 = p1 + (size_t)w * 65536 + lane * 16;

  // ---- resident L0 tiles 0..7 (per wave), loaded once ----
#pragma unroll
  for (int j = 0; j < 8; ++j)
    wres[w * 512 + j * 64 + lane] = *(const uint4*)(gp0 + (size_t)j * 1024);

  // 8-deep direct global->VGPR stream for the non-resident tiles.
  // prologue: L0 streamed tiles 8..15 -> breg[0..7]  (slot = j&7)
  v4i breg[8];
#pragma unroll
  for (int s = 0; s < 8; ++s)
    breg[s] = *(const v4i*)(gp0 + (size_t)(8 + s) * 1024);

  __syncthreads();

#pragma unroll 1
  for (int t = 0; t < TSTEPS; ++t) {
    const int xc = (t & 1) << 9;                   // uint4-index base of X_cur
    const int xn = xc ^ 512;                       // X_next

    // ---- teacher-forced input: each thread loads its own 4 rows ----
    float4 xa[4], xb[4];
    if (t > 0) {
      const float* xp = target + (size_t)(b0 + myrow) * (TSTEPS * DDIM)
                               + (size_t)(t - 1) * DDIM;
#pragma unroll
      for (int r = 0; r < 4; ++r) {
        xa[r] = *(const float4*)(xp + (size_t)r * (TSTEPS * DDIM));
        xb[r] = *(const float4*)(xp + (size_t)r * (TSTEPS * DDIM) + 4);
      }
    } else {
#pragma unroll
      for (int r = 0; r < 4; ++r) {
        xa[r] = make_float4(0.f, 0.f, 0.f, 0.f);
        xb[r] = make_float4(0.f, 0.f, 0.f, 0.f);
      }
    }

    const float sc0 = (t <= 1) ? 4.f : 1.f;
    const float sc1 = (t == 0) ? 4.f : 1.f;
    const float wq0 = (t == 0) ? 31.75f : 127.f;

    v4i acch[8], accl[8];
    const v4i zi = {0, 0, 0, 0};

    // ============ layer 0: h0 @ Whh0 ============
#pragma unroll
    for (int i = 0; i < 8; ++i) { acch[i] = zi; accl[i] = zi; }
    {
      v4i ah, al;
      {                                            // kc=0 A-fragment
        int aidx = xc + (16 + lq) * 16 + l15;
        ah = __builtin_bit_cast(v4i, X4h[aidx]);
        al = __builtin_bit_cast(v4i, X4l[aidx]);
      }
      // resident tiles 0..7 from LDS: explicit 2-slot rotation (static idx)
      {
        v4i rb[2];
        rb[0] = __builtin_bit_cast(v4i, wres[w * 512 + lane]);
#pragma unroll
        for (int j = 0; j < 8; ++j) {
          if (j < 7)
            rb[(j + 1) & 1] = __builtin_bit_cast(v4i, wres[w * 512 + (j + 1) * 64 + lane]);
          v4i bb = rb[j & 1];
          acch[j] = __builtin_amdgcn_mfma_i32_16x16x64_i8(ah, bb, acch[j], 0, 0, 0);
          accl[j] = __builtin_amdgcn_mfma_i32_16x16x64_i8(al, bb, accl[j], 0, 0, 0);
        }
      }
      // streamed tiles 8..31 (slot = j&7)
#pragma unroll 8
      for (int j = 8; j < 32; ++j) {
        const int i = j & 7, s = j & 7;
        if (i == 0) {
          int kc = j >> 3;
          int aidx = xc + (16 + kc * 4 + lq) * 16 + l15;
          ah = __builtin_bit_cast(v4i, X4h[aidx]);
          al = __builtin_bit_cast(v4i, X4l[aidx]);
        }
        v4i bb = breg[s];
        acch[i] = __builtin_amdgcn_mfma_i32_16x16x64_i8(ah, bb, acch[i], 0, 0, 0);
        accl[i] = __builtin_amdgcn_mfma_i32_16x16x64_i8(al, bb, accl[i], 0, 0, 0);
        const int jn = j + 8;
        breg[s] = (jn < 32) ? *(const v4i*)(gp0 + (size_t)jn * 1024)
                            : *(const v4i*)(gp1 + (size_t)(jn - 32) * 1024);
      }
    }

    // ---- deferred out-projection for step t-1 (overlaps stream stalls) ----
    if (t > 0) {
      const unsigned short* hf = h1f[(t & 1) ^ 1];
      float s_ = 0.f;
#pragma unroll
      for (int i = 0; i < 16; ++i) {
        ushort4 hx = *(const ushort4*)&hf[opr * WSTR + i * 16 + opq * 4];
        ushort4 wv = *(const ushort4*)&woutT[opd * WSTR + i * 16 + opq * 4];
        s_ += bf2f(hx.x) * bf2f(wv.x) + bf2f(hx.y) * bf2f(wv.y)
            + bf2f(hx.z) * bf2f(wv.z) + bf2f(hx.w) * bf2f(wv.w);
      }
      s_ += __shfl_xor(s_, 1);
      s_ += __shfl_xor(s_, 2);
      if (opq == 0)
        out[(size_t)(b0 + opr) * (TSTEPS * DDIM) + (size_t)(t - 1) * DDIM + opd] =
            s_ + bo_out;
    }

    // ---- cell 0: dequant + fp32 x-path (tables); h0(t) -> X_next ----
    {
#pragma unroll
      for (int cc = 0; cc < 2; ++cc) {
        float gf4[4][4];
#pragma unroll
        for (int g = 0; g < 4; ++g) {
          int i = g * 2 + cc;
          int col = g * 256 + jc0 + cc * 16;
          float4 wa = wxa4[col];
          float4 wb = wxb4[col];
          float cs = csA0[i] * sc0;
#pragma unroll
          for (int r = 0; r < 4; ++r)
            gf4[g][r] = ((float)acch[i][r] + (float)accl[i][r] * (1.f / 254.f)) * cs + bA0[i]
                + xa[r].x * wa.x + xa[r].y * wa.y + xa[r].z * wa.z + xa[r].w * wa.w
                + xb[r].x * wb.x + xb[r].y * wb.y + xb[r].z * wb.z + xb[r].w * wb.w;
        }
#pragma unroll
        for (int r = 0; r < 4; ++r) {
          float iv = sigm(gf4[0][r]);
          float fv = sigm(gf4[1][r]);
          float gv = tanh_(gf4[2][r]);
          float ov = sigm(gf4[3][r]);
          c0r[cc][r] = fv * c0r[cc][r] + iv * gv;
          char hi, lo;
          q8pair(ov * tanh_(c0r[cc][r]), wq0, &hi, &lo);
          int off = (xn + (16 + 2 * w + cc) * 16 + myrow + r) * 16 + l15;
          Xch[off] = hi; Xcl[off] = lo;
        }
      }
    }
    __syncthreads();   // (B) h0(t) visible; L1 prologue tiles 0..7 landed

    // ====== layer 1: [h1(t-1) | h0(t)] @ W1 (64 tiles, slot = j&7) ======
#pragma unroll
    for (int i = 0; i < 8; ++i) { acch[i] = zi; accl[i] = zi; }
    {
      v4i ah, al;
#pragma unroll 8
      for (int j = 0; j < 64; ++j) {
        const int i = j & 7;
        if (i == 0) {
          int kc = j >> 3;                         // 0..3 h1 (cur), 4..7 h0' (next)
          int aidx = (kc < 4) ? (xc + (kc * 4 + lq) * 16 + l15)
                              : (xn + (16 + (kc - 4) * 4 + lq) * 16 + l15);
          ah = __builtin_bit_cast(v4i, X4h[aidx]);
          al = __builtin_bit_cast(v4i, X4l[aidx]);
        }
        acch[i] = __builtin_amdgcn_mfma_i32_16x16x64_i8(ah, breg[i], acch[i], 0, 0, 0);
        accl[i] = __builtin_amdgcn_mfma_i32_16x16x64_i8(al, breg[i], accl[i], 0, 0, 0);
        const int jn = j + 8;
        // wrap: next-step L0 streamed tiles start at 8 (0..7 are resident)
        breg[i] = (jn < 64) ? *(const v4i*)(gp1 + (size_t)jn * 1024)
                            : *(const v4i*)(gp0 + (size_t)(jn - 64 + 8) * 1024);
      }
    }

    // ---- cell 1: writes h1(t) into X_next + bf16 h1f[t&1] ----
#pragma unroll
    for (int cc = 0; cc < 2; ++cc)
#pragma unroll
      for (int r = 0; r < 4; ++r) {
        float di = ((float)acch[0 + cc][r] + (float)accl[0 + cc][r] * (1.f / 254.f));
        float df = ((float)acch[2 + cc][r] + (float)accl[2 + cc][r] * (1.f / 254.f));
        float dg = ((float)acch[4 + cc][r] + (float)accl[4 + cc][r] * (1.f / 254.f));
        float dv = ((float)acch[6 + cc][r] + (float)accl[6 + cc][r] * (1.f / 254.f));
        float iv = sigm(di * csA1[0 + cc] * sc1 + bA1[0 + cc]);
        float fv = sigm(df * csA1[2 + cc] * sc1 + bA1[2 + cc]);
        float gv = tanh_(dg * csA1[4 + cc] * sc1 + bA1[4 + cc]);
        float ov = sigm(dv * csA1[6 + cc] * sc1 + bA1[6 + cc]);
        c1r[cc][r] = fv * c1r[cc][r] + iv * gv;
        float h = ov * tanh_(c1r[cc][r]);
        char hi, lo;
        q8pair(h, 127.f, &hi, &lo);
        int off = (xn + (2 * w + cc) * 16 + myrow + r) * 16 + l15;
        Xch[off] = hi; Xcl[off] = lo;
        h1f[t & 1][(myrow + r) * WSTR + jc0 + cc * 16] = f2bf(h);
      }
    __syncthreads();   // (F) h1(t)/h1f visible; next-step L0 tiles 8..15 landed
  }

  // ---- epilogue: out-projection for the final step ----
  {
    const unsigned short* hf = h1f[(TSTEPS - 1) & 1];
    float s_ = 0.f;
#pragma unroll
    for (int i = 0; i < 16; ++i) {
      ushort4 hx = *(const ushort4*)&hf[opr * WSTR + i * 16 + opq * 4];
      ushort4 wv = *(const ushort4*)&woutT[opd * WSTR + i * 16 + opq * 4];
      s_ += bf2f(hx.x) * bf2f(wv.x) + bf2f(hx.y) * bf2f(wv.y)
          + bf2f(hx.z) * bf2f(wv.z) + bf2f(hx.w) * bf2f(wv.w);
    }
    s_ += __shfl_xor(s_, 1);
    s_ += __shfl_xor(s_, 2);
    if (opq == 0)
      out[(size_t)(b0 + opr) * (TSTEPS * DDIM) + (size_t)(TSTEPS - 1) * DDIM + opd] =
          s_ + bo_out;
  }
}

extern "C" void kernel_launch(void* const* d_in, const int* in_sizes, int n_in,
                              void* d_out, int out_size, void* d_ws, size_t ws_size,
                              hipStream_t stream) {
  const float* z    = (const float*)d_in[0];
  const float* tgt  = (const float*)d_in[1];
  const float* Wfh  = (const float*)d_in[2];
  const float* bfh  = (const float*)d_in[3];
  const float* Wfc  = (const float*)d_in[4];
  const float* bfc  = (const float*)d_in[5];
  const float* Wih0 = (const float*)d_in[6];
  const float* Whh0 = (const float*)d_in[7];
  const float* bih0 = (const float*)d_in[8];
  const float* bhh0 = (const float*)d_in[9];
  const float* Wih1 = (const float*)d_in[10];
  const float* Whh1 = (const float*)d_in[11];
  const float* bih1 = (const float*)d_in[12];
  const float* bhh1 = (const float*)d_in[13];
  const float* Wout = (const float*)d_in[14];
  const float* bout = (const float*)d_in[15];

  // ws layout (bytes), total ~7.09 MB
  char* ws = (char*)d_ws;
  char*  p0   = ws;                                  // 262,144
  char*  p1   = ws + 262144;                         // 524,288
  char*  h0h  = ws + 786432;                         // 524,288
  char*  h0l  = ws + 1310720;                        // 524,288
  char*  h1h  = ws + 1835008;                        // 524,288
  char*  h1l  = ws + 2359296;                        // 524,288
  float* c0s  = (float*)(ws + 2883584);              // 2,097,152
  float* c1s  = (float*)(ws + 4980736);              // 2,097,152
  float* cs0  = (float*)(ws + 7077888);              // 4,096
  float* qs0  = (float*)(ws + 7081984);              // 4,096
  float* cs1  = (float*)(ws + 7086080);              // 4,096
  float* qs1  = (float*)(ws + 7090176);              // 4,096

  hipLaunchKernelGGL(init_state, dim3(BSZ * HDIM / 256), dim3(256), 0, stream,
                     z, Wfh, bfh, Wfc, bfc, h0h, h0l, h1h, h1l, c0s, c1s);
  hipLaunchKernelGGL(col_scales, dim3(8), dim3(256), 0, stream,
                     Whh0, Wih1, Whh1, cs0, qs0, cs1, qs1);
  hipLaunchKernelGGL(pack_i8, dim3(192), dim3(256), 0, stream,
                     Whh0, Wih1, Whh1, qs0, qs1, p0, p1);
  hipLaunchKernelGGL(lstm_run, dim3(NWG), dim3(NTH), 0, stream,
                     tgt, p0, p1, bih0, bhh0, bih1, bhh1, Wih0, Wout, bout,
                     h0h, h0l, h1h, h1l, c0s, c1s, cs0, cs1, (float*)d_out);
}